// Round 1
// baseline (352.000 us; speedup 1.0000x reference)
//
#include <hip/hip_runtime.h>

// Problem: MultiHeadAttention  B=2, T=2048, D=1024, NH=16, HD=64
// y = softmax(mask(QK^T/sqrt(64))) V projected; torch-Linear convention y = x @ W^T.
//
// Pipeline:
//   cast x,Wq,Wk,Wv,Wo -> bf16 (ws)
//   Q = x@Wq^T  -> [b,h,t,d]   (bf16, ws)
//   K = x@Wk^T  -> [b,h,t,d]   (bf16, ws)
//   Vt = x@Wv^T -> [b,h,d,t]   (bf16, ws, transposed for contiguous PV B-operand reads)
//   O = flashattn(Q,K,Vt) -> [b,t,D] (bf16, ws)
//   out = O@Wo^T + bo -> fp32 d_out
//
// ws usage: 8+8+8+8+8+8 + small = ~50.3 MB

typedef __bf16 bf16x8 __attribute__((ext_vector_type(8)));
typedef float f32x4 __attribute__((ext_vector_type(4)));
typedef unsigned short ushortx8 __attribute__((ext_vector_type(8)));
typedef unsigned short ushortx4 __attribute__((ext_vector_type(4)));

#define T_SEQ 2048
#define NHEAD 16
#define HDIM 64
#define DMODEL 1024

__device__ inline unsigned short f2bf(float f) {
  unsigned int u = __builtin_bit_cast(unsigned int, f);
  unsigned int r = (u + 0x7fffu + ((u >> 16) & 1u)) >> 16;
  return (unsigned short)r;
}

__global__ void cast_f32_bf16(const float* __restrict__ in,
                              unsigned short* __restrict__ out, int n) {
  int i = (blockIdx.x * 256 + threadIdx.x) * 4;
  if (i >= n) return;
  float4 v = *reinterpret_cast<const float4*>(in + i);
  ushortx4 o;
  o[0] = f2bf(v.x); o[1] = f2bf(v.y); o[2] = f2bf(v.z); o[3] = f2bf(v.w);
  *reinterpret_cast<ushortx4*>(out + i) = o;
}

// C[M,N] = A[M,K] * Bw[N,K]^T  (both bf16 row-major, k contiguous)
// MODE 0: write bf16 to out[((b*NH+h)*T + t)*HD + d]   (row=b*T+t, col=h*HD+d)
// MODE 1: write bf16 to out[((b*NH+h)*HD + d)*T + t]   (V transposed)
// MODE 3: write fp32 out[row*N+col] + bias[col]
template <int MODE>
__global__ __launch_bounds__(256) void gemm_bt(
    const unsigned short* __restrict__ A, const unsigned short* __restrict__ Bw,
    void* __restrict__ outp, const float* __restrict__ bias,
    int M, int N, int K) {
  __shared__ unsigned short As[128][40];  // pad 32->40: frag reads 2-way (free)
  __shared__ unsigned short Bs[128][40];
  const int tid = threadIdx.x;
  const int lane = tid & 63, wid = tid >> 6;
  const int wr = wid >> 1, wc = wid & 1;
  const int lr = lane & 15, lg = lane >> 4;
  const int m0 = blockIdx.y * 128, n0 = blockIdx.x * 128;
  const int sr = tid >> 2;        // staging row 0..63
  const int sc = (tid & 3) * 8;   // staging col 0,8,16,24

  f32x4 acc[4][4] = {};

  for (int k0 = 0; k0 < K; k0 += 32) {
    ushortx8 a0 = *reinterpret_cast<const ushortx8*>(A + (size_t)(m0 + sr) * K + k0 + sc);
    ushortx8 a1 = *reinterpret_cast<const ushortx8*>(A + (size_t)(m0 + sr + 64) * K + k0 + sc);
    ushortx8 b0 = *reinterpret_cast<const ushortx8*>(Bw + (size_t)(n0 + sr) * K + k0 + sc);
    ushortx8 b1 = *reinterpret_cast<const ushortx8*>(Bw + (size_t)(n0 + sr + 64) * K + k0 + sc);
    __syncthreads();
    *reinterpret_cast<ushortx8*>(&As[sr][sc]) = a0;
    *reinterpret_cast<ushortx8*>(&As[sr + 64][sc]) = a1;
    *reinterpret_cast<ushortx8*>(&Bs[sr][sc]) = b0;
    *reinterpret_cast<ushortx8*>(&Bs[sr + 64][sc]) = b1;
    __syncthreads();

    bf16x8 af[4], bfr[4];
#pragma unroll
    for (int i = 0; i < 4; ++i) {
      af[i]  = *reinterpret_cast<const bf16x8*>(&As[wr * 64 + i * 16 + lr][lg * 8]);
      bfr[i] = *reinterpret_cast<const bf16x8*>(&Bs[wc * 64 + i * 16 + lr][lg * 8]);
    }
#pragma unroll
    for (int mi = 0; mi < 4; ++mi)
#pragma unroll
      for (int ni = 0; ni < 4; ++ni)
        acc[mi][ni] = __builtin_amdgcn_mfma_f32_16x16x32_bf16(af[mi], bfr[ni], acc[mi][ni], 0, 0, 0);
  }

  const int mb = m0 + wr * 64, nb = n0 + wc * 64;
#pragma unroll
  for (int mi = 0; mi < 4; ++mi) {
#pragma unroll
    for (int ni = 0; ni < 4; ++ni) {
      const int col = nb + ni * 16 + lr;
#pragma unroll
      for (int j = 0; j < 4; ++j) {
        const int row = mb + mi * 16 + lg * 4 + j;
        const float v = acc[mi][ni][j];
        if (MODE == 0) {
          const int b = row >> 11, t = row & (T_SEQ - 1);
          const int h = col >> 6, d = col & (HDIM - 1);
          ((unsigned short*)outp)[(((size_t)(b * NHEAD + h) * T_SEQ + t) << 6) + d] = f2bf(v);
        } else if (MODE == 1) {
          const int b = row >> 11, t = row & (T_SEQ - 1);
          const int h = col >> 6, d = col & (HDIM - 1);
          ((unsigned short*)outp)[(((size_t)(b * NHEAD + h) * HDIM + d) << 11) + t] = f2bf(v);
        } else {
          ((float*)outp)[(size_t)row * N + col] = v + bias[col];
        }
      }
    }
  }
}

// Flash attention, causal. Q,K: [b,h,t,d] bf16; Vt: [b,h,d,t] bf16; O: [b,t,D] bf16.
// Block: 256 thr = 4 waves; wave w owns q rows [blk*64 + w*16, +16). grid (T/64, B*NH).
__global__ __launch_bounds__(256) void flash_attn(
    const unsigned short* __restrict__ Q, const unsigned short* __restrict__ Kb,
    const unsigned short* __restrict__ Vt, unsigned short* __restrict__ O) {
  __shared__ unsigned short Pl[4][16][40];  // per-wave P transpose tile, padded
  const int tid = threadIdx.x, lane = tid & 63, wid = tid >> 6;
  const int lr = lane & 15, lg = lane >> 4;
  const int bh = blockIdx.y;
  const int qg = blockIdx.x * 64 + wid * 16;
  const size_t baseQK = (size_t)bh * T_SEQ * HDIM;
  const size_t baseVt = (size_t)bh * HDIM * T_SEQ;
  const float scale = 0.125f;  // 1/sqrt(64)

  // Q fragments (rows qg+lr, d split in two 32-halves)
  bf16x8 qf[2];
#pragma unroll
  for (int kk = 0; kk < 2; ++kk)
    qf[kk] = *reinterpret_cast<const bf16x8*>(Q + baseQK + (size_t)(qg + lr) * HDIM + kk * 32 + lg * 8);

  f32x4 acco[4] = {};
  float mrun[4], lrun[4];
#pragma unroll
  for (int j = 0; j < 4; ++j) { mrun[j] = -INFINITY; lrun[j] = 0.f; }

  const int ntiles = ((qg + 15) >> 5) + 1;
  for (int kt = 0; kt < ntiles; ++kt) {
    const int kb = kt * 32;
    // S = Q K^T  (two 16-col fragments)
    f32x4 s[2] = {};
#pragma unroll
    for (int c = 0; c < 2; ++c)
#pragma unroll
      for (int kk = 0; kk < 2; ++kk) {
        bf16x8 kf = *reinterpret_cast<const bf16x8*>(
            Kb + baseQK + (size_t)(kb + c * 16 + lr) * HDIM + kk * 32 + lg * 8);
        s[c] = __builtin_amdgcn_mfma_f32_16x16x32_bf16(qf[kk], kf, s[c], 0, 0, 0);
      }
    // scale + causal mask + tile row-max
    float tmax[4] = {-INFINITY, -INFINITY, -INFINITY, -INFINITY};
#pragma unroll
    for (int c = 0; c < 2; ++c)
#pragma unroll
      for (int j = 0; j < 4; ++j) {
        const int qrow = qg + lg * 4 + j;
        const int kcol = kb + c * 16 + lr;
        float v = s[c][j] * scale;
        if (kcol > qrow) v = -INFINITY;
        s[c][j] = v;
        tmax[j] = fmaxf(tmax[j], v);
      }
#pragma unroll
    for (int m = 1; m < 16; m <<= 1)
#pragma unroll
      for (int j = 0; j < 4; ++j)
        tmax[j] = fmaxf(tmax[j], __shfl_xor(tmax[j], m, 64));
    // online softmax update
    float fac[4];
#pragma unroll
    for (int j = 0; j < 4; ++j) {
      const float mnew = fmaxf(mrun[j], tmax[j]);  // finite after tile 0
      fac[j] = __expf(mrun[j] - mnew);
      mrun[j] = mnew;
    }
    float tsum[4] = {0.f, 0.f, 0.f, 0.f};
#pragma unroll
    for (int c = 0; c < 2; ++c)
#pragma unroll
      for (int j = 0; j < 4; ++j) {
        const float p = __expf(s[c][j] - mrun[j]);  // exp(-inf)=0 handles mask
        s[c][j] = p;
        tsum[j] += p;
      }
#pragma unroll
    for (int m = 1; m < 16; m <<= 1)
#pragma unroll
      for (int j = 0; j < 4; ++j)
        tsum[j] += __shfl_xor(tsum[j], m, 64);
#pragma unroll
    for (int j = 0; j < 4; ++j) lrun[j] = lrun[j] * fac[j] + tsum[j];
#pragma unroll
    for (int d = 0; d < 4; ++d)
#pragma unroll
      for (int j = 0; j < 4; ++j) acco[d][j] *= fac[j];
    // P -> LDS (true (q,k) indices), read back as A-fragment (same k-slot formula
    // as the V B-fragment below -> any HW k-slot permutation cancels)
#pragma unroll
    for (int c = 0; c < 2; ++c)
#pragma unroll
      for (int j = 0; j < 4; ++j)
        Pl[wid][lg * 4 + j][c * 16 + lr] = f2bf(s[c][j]);
    bf16x8 pa = *reinterpret_cast<const bf16x8*>(&Pl[wid][lr][lg * 8]);
#pragma unroll
    for (int d = 0; d < 4; ++d) {
      bf16x8 vf = *reinterpret_cast<const bf16x8*>(
          Vt + baseVt + (size_t)(d * 16 + lr) * T_SEQ + kb + lg * 8);
      acco[d] = __builtin_amdgcn_mfma_f32_16x16x32_bf16(pa, vf, acco[d], 0, 0, 0);
    }
  }
  // epilogue: O[b, t, h*64 + d]
  const int b = bh >> 4, h = bh & (NHEAD - 1);
#pragma unroll
  for (int d = 0; d < 4; ++d)
#pragma unroll
    for (int j = 0; j < 4; ++j) {
      const int t = qg + lg * 4 + j;
      const float v = acco[d][j] / lrun[j];
      O[(((size_t)(b * T_SEQ + t)) << 10) + h * HDIM + d * 16 + lr] = f2bf(v);
    }
}

extern "C" void kernel_launch(void* const* d_in, const int* in_sizes, int n_in,
                              void* d_out, int out_size, void* d_ws, size_t ws_size,
                              hipStream_t stream) {
  const float* x  = (const float*)d_in[0];
  const float* Wq = (const float*)d_in[1];
  const float* Wk = (const float*)d_in[2];
  const float* Wv = (const float*)d_in[3];
  const float* Wo = (const float*)d_in[4];
  const float* bo = (const float*)d_in[5];
  float* out = (float*)d_out;

  const int M = 2 * T_SEQ;          // 4096
  const int NXD = DMODEL * DMODEL;  // 1048576
  const int NX = M * DMODEL;        // 4194304

  unsigned short* ws = (unsigned short*)d_ws;
  unsigned short* xb  = ws;            // 4194304
  unsigned short* Wqb = xb + NX;       // 1048576
  unsigned short* Wkb = Wqb + NXD;
  unsigned short* Wvb = Wkb + NXD;
  unsigned short* Wob = Wvb + NXD;
  unsigned short* Qb  = Wob + NXD;     // 4194304 [b,h,t,d]
  unsigned short* Kbf = Qb + NX;       // [b,h,t,d]
  unsigned short* Vtb = Kbf + NX;      // [b,h,d,t]
  unsigned short* Ob  = Vtb + NX;      // [b,t,D]
  // total: 25165824 ushorts = 50.3 MB

  cast_f32_bf16<<<NX / 1024, 256, 0, stream>>>(x, xb, NX);
  cast_f32_bf16<<<NXD / 1024, 256, 0, stream>>>(Wq, Wqb, NXD);
  cast_f32_bf16<<<NXD / 1024, 256, 0, stream>>>(Wk, Wkb, NXD);
  cast_f32_bf16<<<NXD / 1024, 256, 0, stream>>>(Wv, Wvb, NXD);
  cast_f32_bf16<<<NXD / 1024, 256, 0, stream>>>(Wo, Wob, NXD);

  dim3 gg(DMODEL / 128, M / 128);  // (8, 32)
  gemm_bt<0><<<gg, 256, 0, stream>>>(xb, Wqb, Qb,  nullptr, M, DMODEL, DMODEL);
  gemm_bt<0><<<gg, 256, 0, stream>>>(xb, Wkb, Kbf, nullptr, M, DMODEL, DMODEL);
  gemm_bt<1><<<gg, 256, 0, stream>>>(xb, Wvb, Vtb, nullptr, M, DMODEL, DMODEL);

  dim3 ga(T_SEQ / 64, 2 * NHEAD);  // (32, 32)
  flash_attn<<<ga, 256, 0, stream>>>(Qb, Kbf, Vtb, Ob);

  gemm_bt<3><<<gg, 256, 0, stream>>>(Ob, Wob, out, bo, M, DMODEL, DMODEL);
}

// Round 2
// 350.896 us; speedup vs baseline: 1.0031x; 1.0031x over previous
//
#include <hip/hip_runtime.h>

// MultiHeadAttention  B=2, T=2048, D=1024, NH=16, HD=64
// Round 2: swapped-QK flash (lane-local softmax rows), KVBLK=64,
// longest-first causal ordering, global_load_lds GEMM staging.

typedef __bf16 bf16x8 __attribute__((ext_vector_type(8)));
typedef float f32x4 __attribute__((ext_vector_type(4)));
typedef unsigned short ushortx8 __attribute__((ext_vector_type(8)));
typedef unsigned short ushortx4 __attribute__((ext_vector_type(4)));

#define T_SEQ 2048
#define NHEAD 16
#define HDIM 64
#define DMODEL 1024

__device__ inline unsigned short f2bf(float f) {
  unsigned int u = __builtin_bit_cast(unsigned int, f);
  unsigned int r = (u + 0x7fffu + ((u >> 16) & 1u)) >> 16;
  return (unsigned short)r;
}

__device__ inline void gl16(const unsigned short* g, unsigned short* l) {
  __builtin_amdgcn_global_load_lds(
      (const __attribute__((address_space(1))) unsigned int*)g,
      (__attribute__((address_space(3))) unsigned int*)l, 16, 0, 0);
}

__global__ void cast_f32_bf16(const float* __restrict__ in,
                              unsigned short* __restrict__ out, int n) {
  int i = (blockIdx.x * 256 + threadIdx.x) * 4;
  if (i >= n) return;
  float4 v = *reinterpret_cast<const float4*>(in + i);
  ushortx4 o;
  o[0] = f2bf(v.x); o[1] = f2bf(v.y); o[2] = f2bf(v.z); o[3] = f2bf(v.w);
  *reinterpret_cast<ushortx4*>(out + i) = o;
}

// C[M,N] = A[M,K] * Bw[N,K]^T  (bf16 row-major, k contiguous)
// MODE 0: bf16 out[((b*NH+h)*T + t)*HD + d]
// MODE 1: bf16 out[((b*NH+h)*HD + d)*T + t]  (V transposed)
// MODE 3: fp32 out[row*N+col] + bias[col]
template <int MODE>
__global__ __launch_bounds__(256) void gemm_bt(
    const unsigned short* __restrict__ A, const unsigned short* __restrict__ Bw,
    void* __restrict__ outp, const float* __restrict__ bias,
    int M, int N, int K) {
  __shared__ unsigned short As[128 * 32];  // linear: row*32 + col (gload_lds needs it)
  __shared__ unsigned short Bs[128 * 32];
  const int tid = threadIdx.x;
  const int lane = tid & 63, wid = tid >> 6;
  const int wr = wid >> 1, wc = wid & 1;
  const int lr = lane & 15, lg = lane >> 4;
  const int m0 = blockIdx.y * 128, n0 = blockIdx.x * 128;

  // staging: thread t -> row t>>2 (and +64), 16B chunk (t&3). LDS dest = base + tid*16B.
  const unsigned short* ga0 = A + (size_t)(m0 + (tid >> 2)) * K + (tid & 3) * 8;
  const unsigned short* gb0 = Bw + (size_t)(n0 + (tid >> 2)) * K + (tid & 3) * 8;
  unsigned short* la0 = As + tid * 8;
  unsigned short* lb0 = Bs + tid * 8;

  f32x4 acc[4][4] = {};

  for (int k0 = 0; k0 < K; k0 += 32) {
    __syncthreads();  // previous frag reads done before overwrite
    gl16(ga0 + k0, la0);
    gl16(ga0 + (size_t)64 * K + k0, la0 + 2048);
    gl16(gb0 + k0, lb0);
    gl16(gb0 + (size_t)64 * K + k0, lb0 + 2048);
    __syncthreads();  // compiler drains vmcnt before s_barrier

    bf16x8 af[4], bfr[4];
#pragma unroll
    for (int i = 0; i < 4; ++i) {
      af[i]  = *reinterpret_cast<const bf16x8*>(&As[(wr * 64 + i * 16 + lr) * 32 + lg * 8]);
      bfr[i] = *reinterpret_cast<const bf16x8*>(&Bs[(wc * 64 + i * 16 + lr) * 32 + lg * 8]);
    }
#pragma unroll
    for (int mi = 0; mi < 4; ++mi)
#pragma unroll
      for (int ni = 0; ni < 4; ++ni)
        acc[mi][ni] = __builtin_amdgcn_mfma_f32_16x16x32_bf16(af[mi], bfr[ni], acc[mi][ni], 0, 0, 0);
  }

  const int mb = m0 + wr * 64, nb = n0 + wc * 64;
#pragma unroll
  for (int mi = 0; mi < 4; ++mi) {
#pragma unroll
    for (int ni = 0; ni < 4; ++ni) {
      const int col = nb + ni * 16 + lr;
#pragma unroll
      for (int j = 0; j < 4; ++j) {
        const int row = mb + mi * 16 + lg * 4 + j;
        const float v = acc[mi][ni][j];
        if (MODE == 0) {
          const int b = row >> 11, t = row & (T_SEQ - 1);
          const int h = col >> 6, d = col & (HDIM - 1);
          ((unsigned short*)outp)[(((size_t)(b * NHEAD + h) * T_SEQ + t) << 6) + d] = f2bf(v);
        } else if (MODE == 1) {
          const int b = row >> 11, t = row & (T_SEQ - 1);
          const int h = col >> 6, d = col & (HDIM - 1);
          ((unsigned short*)outp)[(((size_t)(b * NHEAD + h) * HDIM + d) << 11) + t] = f2bf(v);
        } else {
          ((float*)outp)[(size_t)row * N + col] = v + bias[col];
        }
      }
    }
  }
}

// Flash attention, causal, swapped QK^T. Q,K: [b,h,t,d]; Vt: [b,h,d,t]; O: [b,t,D].
// 4 waves/block, wave owns 16 q rows, KVBLK=64. grid (T/64, B*NH), longest-first.
// s = mfma(K,Q): lane holds S^T[k = kb+c*16+lg*4+j][q = qg+lr] -> softmax row is
// lane-local except a 4-lane (lg) reduce: 2 shfl_xor per pass.
__global__ __launch_bounds__(256, 4) void flash_attn(
    const unsigned short* __restrict__ Q, const unsigned short* __restrict__ Kg,
    const unsigned short* __restrict__ Vt, unsigned short* __restrict__ O) {
  // P tile per wave: [ks=2][lr=16][40] (stride 40 elems = 80B, 16B-aligned rows)
  __shared__ unsigned short Pl[4][2][16][40];
  const int tid = threadIdx.x, lane = tid & 63, wid = tid >> 6;
  const int lr = lane & 15, lg = lane >> 4;
  const int bh = blockIdx.y;
  const int qblk = gridDim.x - 1 - blockIdx.x;  // longest-first
  const int qg = qblk * 64 + wid * 16;
  const size_t baseQK = (size_t)bh * (T_SEQ * HDIM);
  const float scale = 0.125f;  // 1/sqrt(64)

  // Q fragments (B-operand): lane <- q row qg+lr, d chunk h*32 + lg*8
  bf16x8 qf[2];
#pragma unroll
  for (int h = 0; h < 2; ++h)
    qf[h] = *reinterpret_cast<const bf16x8*>(Q + baseQK + (size_t)(qg + lr) * HDIM + h * 32 + lg * 8);

  float mrun = -INFINITY, lrun = 0.f;
  f32x4 acco[4] = {};  // acco[d][j] = O[q=qg+lg*4+j][d*16+lr]
  const int ntiles = qblk + 1;  // uniform across the block's waves
  const int q = qg + lr;

  for (int kt = 0; kt < ntiles; ++kt) {
    const int kb = kt * 64;
    // S^T = K Q^T : A = K rows (kb+c*16+lr, chunk lg), B = Q (loop-invariant)
    f32x4 s[4] = {};
#pragma unroll
    for (int c = 0; c < 4; ++c) {
#pragma unroll
      for (int h = 0; h < 2; ++h) {
        bf16x8 kf = *reinterpret_cast<const bf16x8*>(
            Kg + baseQK + (size_t)(kb + c * 16 + lr) * HDIM + h * 32 + lg * 8);
        s[c] = __builtin_amdgcn_mfma_f32_16x16x32_bf16(kf, qf[h], s[c], 0, 0, 0);
      }
    }
    // scale + causal mask + lane-local row max
    float tm = -INFINITY;
#pragma unroll
    for (int c = 0; c < 4; ++c)
#pragma unroll
      for (int j = 0; j < 4; ++j) {
        const int k = kb + c * 16 + lg * 4 + j;
        float v = s[c][j] * scale;
        v = (k <= q) ? v : -INFINITY;
        s[c][j] = v;
        tm = fmaxf(tm, v);
      }
    tm = fmaxf(tm, __shfl_xor(tm, 16, 64));
    tm = fmaxf(tm, __shfl_xor(tm, 32, 64));
    const float mnew = fmaxf(mrun, tm);  // finite: k=kb<=q always in-tile
    const float fac = __expf(mrun - mnew);
    float tsum = 0.f;
#pragma unroll
    for (int c = 0; c < 4; ++c)
#pragma unroll
      for (int j = 0; j < 4; ++j) {
        const float p = __expf(s[c][j] - mnew);  // exp(-inf)=0 kills masked
        s[c][j] = p;
        tsum += p;
      }
    tsum += __shfl_xor(tsum, 16, 64);
    tsum += __shfl_xor(tsum, 32, 64);
    lrun = lrun * fac + tsum;
    mrun = mnew;
    // rescale acco: factor for q-row lg*4+j lives in lane lg*4+j
    float facj[4];
#pragma unroll
    for (int j = 0; j < 4; ++j) facj[j] = __shfl(fac, lg * 4 + j, 64);
#pragma unroll
    for (int d = 0; d < 4; ++d)
#pragma unroll
      for (int j = 0; j < 4; ++j) acco[d][j] *= facj[j];
    // P -> LDS: P[q=lr][k=c*16+lg*4 ..+4], split into two 32-wide ks groups
#pragma unroll
    for (int c = 0; c < 4; ++c) {
      unsigned int lo = (unsigned int)f2bf(s[c][0]) | ((unsigned int)f2bf(s[c][1]) << 16);
      unsigned int hi = (unsigned int)f2bf(s[c][2]) | ((unsigned int)f2bf(s[c][3]) << 16);
      uint2 w; w.x = lo; w.y = hi;
      *reinterpret_cast<uint2*>(&Pl[wid][c >> 1][lr][(c & 1) * 16 + lg * 4]) = w;
    }
    bf16x8 pa[2];
#pragma unroll
    for (int ks = 0; ks < 2; ++ks)
      pa[ks] = *reinterpret_cast<const bf16x8*>(&Pl[wid][ks][lr][lg * 8]);
    // PV: A = P (q rows), B = V (d cols via Vt rows), k chunks ks*32+lg*8
#pragma unroll
    for (int d = 0; d < 4; ++d) {
#pragma unroll
      for (int ks = 0; ks < 2; ++ks) {
        bf16x8 vf = *reinterpret_cast<const bf16x8*>(
            Vt + baseQK + (size_t)(d * 16 + lr) * T_SEQ + kb + ks * 32 + lg * 8);
        acco[d] = __builtin_amdgcn_mfma_f32_16x16x32_bf16(pa[ks], vf, acco[d], 0, 0, 0);
      }
    }
  }
  // epilogue: O[b, t, h*64 + d]; l for q-row lg*4+j lives in lane lg*4+j
  const int b = bh >> 4, h = bh & (NHEAD - 1);
  float lj[4];
#pragma unroll
  for (int j = 0; j < 4; ++j) lj[j] = __shfl(lrun, lg * 4 + j, 64);
#pragma unroll
  for (int d = 0; d < 4; ++d)
#pragma unroll
    for (int j = 0; j < 4; ++j) {
      const int t = qg + lg * 4 + j;
      const float v = acco[d][j] / lj[j];
      O[(((size_t)(b * T_SEQ + t)) << 10) + h * HDIM + d * 16 + lr] = f2bf(v);
    }
}

extern "C" void kernel_launch(void* const* d_in, const int* in_sizes, int n_in,
                              void* d_out, int out_size, void* d_ws, size_t ws_size,
                              hipStream_t stream) {
  const float* x  = (const float*)d_in[0];
  const float* Wq = (const float*)d_in[1];
  const float* Wk = (const float*)d_in[2];
  const float* Wv = (const float*)d_in[3];
  const float* Wo = (const float*)d_in[4];
  const float* bo = (const float*)d_in[5];
  float* out = (float*)d_out;

  const int M = 2 * T_SEQ;          // 4096
  const int NXD = DMODEL * DMODEL;  // 1048576
  const int NX = M * DMODEL;        // 4194304

  unsigned short* ws = (unsigned short*)d_ws;
  unsigned short* xb  = ws;
  unsigned short* Wqb = xb + NX;
  unsigned short* Wkb = Wqb + NXD;
  unsigned short* Wvb = Wkb + NXD;
  unsigned short* Wob = Wvb + NXD;
  unsigned short* Qb  = Wob + NXD;   // [b,h,t,d]
  unsigned short* Kbf = Qb + NX;     // [b,h,t,d]
  unsigned short* Vtb = Kbf + NX;    // [b,h,d,t]
  unsigned short* Ob  = Vtb + NX;    // [b,t,D]

  cast_f32_bf16<<<NX / 1024, 256, 0, stream>>>(x, xb, NX);
  cast_f32_bf16<<<NXD / 1024, 256, 0, stream>>>(Wq, Wqb, NXD);
  cast_f32_bf16<<<NXD / 1024, 256, 0, stream>>>(Wk, Wkb, NXD);
  cast_f32_bf16<<<NXD / 1024, 256, 0, stream>>>(Wv, Wvb, NXD);
  cast_f32_bf16<<<NXD / 1024, 256, 0, stream>>>(Wo, Wob, NXD);

  dim3 gg(DMODEL / 128, M / 128);  // (8, 32)
  gemm_bt<0><<<gg, 256, 0, stream>>>(xb, Wqb, Qb,  nullptr, M, DMODEL, DMODEL);
  gemm_bt<0><<<gg, 256, 0, stream>>>(xb, Wkb, Kbf, nullptr, M, DMODEL, DMODEL);
  gemm_bt<1><<<gg, 256, 0, stream>>>(xb, Wvb, Vtb, nullptr, M, DMODEL, DMODEL);

  dim3 ga(T_SEQ / 64, 2 * NHEAD);  // (32, 32)
  flash_attn<<<ga, 256, 0, stream>>>(Qb, Kbf, Vtb, Ob);

  gemm_bt<3><<<gg, 256, 0, stream>>>(Ob, Wob, out, bo, M, DMODEL, DMODEL);
}